// Round 15
// baseline (139.636 us; speedup 1.0000x reference)
//
#include <hip/hip_runtime.h>
#include <hip/hip_bf16.h>

// CrossViewAttention: B=4, V=6, C=256, H=W=64 (HW=4096), heads=8, dh=32.
//
// Pipeline (3 launches): convert_weights, transpose_mean, mega_kernel.
//
// Round-15 mega: wave-role split. 1024 threads = 16 waves; block owns 32 px.
//   K-waves (0-7, head h): Wk head-slice RESIDENT in 64 VGPR; Q GEMM + qb;
//     per view: gemmK (LDS A + reg B), scores via lane-local product +
//     16-lane shfl butterfly, online-softmax stats, publish (e,f) to LDS.
//   V-waves (8-15, head h): Wv slice resident; per view: gemmV, then after
//     the barrier fold oacc = oacc*f + e*Vacc (overlaps K's next gemm).
//   Role branches are disjoint top-level 'if's so bkreg/bvreg live ranges
//   never overlap -> no 128-VGPR spill (rounds 9-13's poison). Inner loop has
//   ZERO global loads. One barrier per view. LDS 37 KB, 4 waves/SIMD.
// (Round-14 failed: a 256x256 bf16 matrix is 128 KB/matrix -> Wk+Wv = 256 KB
//  cannot live in LDS; stageW overflowed its 64 KB buffer.)

typedef __bf16 bf16x8 __attribute__((ext_vector_type(8)));
typedef __bf16 bf16x4 __attribute__((ext_vector_type(4)));
typedef float f32x4 __attribute__((ext_vector_type(4)));

#define HW 4096
#define C_DIM 256
#define NV 6
#define NB 4

__global__ __launch_bounds__(256) void convert_weights_kernel(
    const float* __restrict__ Wq, const float* __restrict__ Wk,
    const float* __restrict__ Wv, const float* __restrict__ Wo,
    __hip_bfloat16* __restrict__ out)
{
    const float* srcs[4] = {Wq, Wk, Wv, Wo};
    const int m = blockIdx.y;
    const int i = blockIdx.x * 256 + threadIdx.x;
    out[m * 65536 + i] = __float2bfloat16(srcs[m][i]);
}

// 64x64 tile transpose via LDS; accumulates per-view sum for xbar.
__global__ __launch_bounds__(256) void transpose_mean_kernel(
    const float* __restrict__ x,        // [B][V][C][HW]
    __hip_bfloat16* __restrict__ xt,    // [B][V][HW][C]
    __hip_bfloat16* __restrict__ xbar)  // [B][HW][C]
{
    __shared__ float tile[64][65];
    const int w0 = blockIdx.x * 64;
    const int c0 = blockIdx.y * 64;
    const int b  = blockIdx.z;
    const int t  = threadIdx.x;
    const int li = t & 63;
    const int qi = t >> 6;
    float acc[16];
#pragma unroll
    for (int i = 0; i < 16; ++i) acc[i] = 0.f;

    for (int v = 0; v < NV; ++v) {
        const float* src = x + (((size_t)b * NV + v) * C_DIM + c0) * HW + w0;
#pragma unroll
        for (int i = 0; i < 16; ++i) {
            const int c = qi + 4 * i;
            tile[li][c] = src[(size_t)c * HW + li];
        }
        __syncthreads();
        __hip_bfloat16* dst = xt + (((size_t)b * NV + v) * HW + w0) * C_DIM + c0;
#pragma unroll
        for (int i = 0; i < 16; ++i) {
            const int w = qi + 4 * i;
            const float val = tile[w][li];
            acc[i] += val;
            dst[(size_t)w * C_DIM + li] = __float2bfloat16(val);
        }
        __syncthreads();
    }
    __hip_bfloat16* dbar = xbar + ((size_t)b * HW + w0) * C_DIM + c0;
#pragma unroll
    for (int i = 0; i < 16; ++i) {
        const int w = qi + 4 * i;
        dbar[(size_t)w * C_DIM + li] = __float2bfloat16(acc[i] * (1.f / 6.f));
    }
}

// Mega kernel v4: 1024 threads (16 waves), block owns 32 pixels of batch b.
// Per-wave GEMM: M=32 (i<2), N=32 (j<2), K=256 (kt<8).
// Abuf layout: [kb 0..31][row 0..31][8] bf16 (16 KB per buffer, dbuf).
// ef[buf][head][row] = (e, f) softmax factors; inv_lds[head][row] = 1/den.
__global__ __launch_bounds__(1024, 4) void mega_kernel(
    const __hip_bfloat16* __restrict__ xt,    // [B*V][4096][256]
    const __hip_bfloat16* __restrict__ xbar,  // [B][4096][256]
    const __hip_bfloat16* __restrict__ Wq,
    const __hip_bfloat16* __restrict__ Wk,
    const __hip_bfloat16* __restrict__ Wv,
    const __hip_bfloat16* __restrict__ Wo,
    float* __restrict__ out)                  // [B][256][4096]
{
    __shared__ __align__(16) __hip_bfloat16 Abuf[2][8192];   // 2 x 16 KB
    __shared__ float ef_lds[2][8][32][2];                    // 4 KB
    __shared__ float inv_lds[8][32];                         // 1 KB
    const size_t SL = (size_t)HW * C_DIM;
    const int w0 = blockIdx.x * 32;
    const int b  = blockIdx.y;
    const int t  = threadIdx.x, wv = t >> 6, l = t & 63;
    const int g = l >> 4, rl = l & 15;

    // stage chunk wv (1 KB) of a 32x256 bf16 tile; 16 waves cover the tile.
    // chunk wv: kb = wv*2 + (l>>5), row = l&31; LDS dest wave-uniform.
    auto stageA = [&](int buf, const __hip_bfloat16* src) {
        const __hip_bfloat16* gp =
            src + (size_t)(w0 + (l & 31)) * 256 + (wv * 2 + (l >> 5)) * 8;
        __builtin_amdgcn_global_load_lds(
            (const __attribute__((address_space(1))) void*)gp,
            (__attribute__((address_space(3))) void*)(&Abuf[buf][wv * 512]),
            16, 0, 0);
    };
    auto ldA = [&](int buf, int kt, int i) -> bf16x8 {
        return *(const bf16x8*)&Abuf[buf][(kt * 4 + g) * 256 + (i * 16 + rl) * 8];
    };

    if (wv < 8) {
        // ================= K-role: head h = wv =================
        const int h = wv;
        bf16x8 bkreg[8][2];
#pragma unroll
        for (int kt = 0; kt < 8; ++kt)
#pragma unroll
            for (int j = 0; j < 2; ++j)
                bkreg[kt][j] = *(const bf16x8*)(Wk + (size_t)(h * 32 + j * 16 + rl) * 256 + kt * 32 + g * 8);
        stageA(0, xt + (size_t)(b * NV) * SL);   // view 0
        stageA(1, xbar + (size_t)b * SL);        // xbar for Q
        __syncthreads();                          // B1: tiles staged

        f32x4 Kacc[2][2];
#pragma unroll
        for (int i = 0; i < 2; ++i)
#pragma unroll
            for (int j = 0; j < 2; ++j) {
                Kacc[i][j][0] = 0.f; Kacc[i][j][1] = 0.f;
                Kacc[i][j][2] = 0.f; Kacc[i][j][3] = 0.f;
            }
#pragma unroll
        for (int kt = 0; kt < 8; ++kt) {
            bf16x8 b0 = *(const bf16x8*)(Wq + (size_t)(h * 32 + rl) * 256 + kt * 32 + g * 8);
            bf16x8 b1 = *(const bf16x8*)(Wq + (size_t)(h * 32 + 16 + rl) * 256 + kt * 32 + g * 8);
            bf16x8 a0 = ldA(1, kt, 0), a1 = ldA(1, kt, 1);
            Kacc[0][0] = __builtin_amdgcn_mfma_f32_16x16x32_bf16(a0, b0, Kacc[0][0], 0, 0, 0);
            Kacc[0][1] = __builtin_amdgcn_mfma_f32_16x16x32_bf16(a0, b1, Kacc[0][1], 0, 0, 0);
            Kacc[1][0] = __builtin_amdgcn_mfma_f32_16x16x32_bf16(a1, b0, Kacc[1][0], 0, 0, 0);
            Kacc[1][1] = __builtin_amdgcn_mfma_f32_16x16x32_bf16(a1, b1, Kacc[1][1], 0, 0, 0);
        }
        const float scale = 0.17677669529663687f; // 32^-0.5
        bf16x4 qb[2][2];
#pragma unroll
        for (int i = 0; i < 2; ++i)
#pragma unroll
            for (int j = 0; j < 2; ++j)
#pragma unroll
                for (int r = 0; r < 4; ++r)
                    qb[i][j][r] = (__bf16)(Kacc[i][j][r] * scale);
        float m[2][4], den[2][4];
#pragma unroll
        for (int i = 0; i < 2; ++i)
#pragma unroll
            for (int r = 0; r < 4; ++r) { m[i][r] = -1e30f; den[i][r] = 0.f; }
        __syncthreads();                          // B2: Q done, Abuf[1] free

        for (int v = 0; v < NV; ++v) {
            const int buf = v & 1;
            if (v < NV - 1) stageA(buf ^ 1, xt + (size_t)(b * NV + v + 1) * SL);
#pragma unroll
            for (int i = 0; i < 2; ++i)
#pragma unroll
                for (int j = 0; j < 2; ++j) {
                    Kacc[i][j][0] = 0.f; Kacc[i][j][1] = 0.f;
                    Kacc[i][j][2] = 0.f; Kacc[i][j][3] = 0.f;
                }
#pragma unroll
            for (int kt = 0; kt < 8; ++kt) {
                bf16x8 a0 = ldA(buf, kt, 0), a1 = ldA(buf, kt, 1);
                Kacc[0][0] = __builtin_amdgcn_mfma_f32_16x16x32_bf16(a0, bkreg[kt][0], Kacc[0][0], 0, 0, 0);
                Kacc[0][1] = __builtin_amdgcn_mfma_f32_16x16x32_bf16(a0, bkreg[kt][1], Kacc[0][1], 0, 0, 0);
                Kacc[1][0] = __builtin_amdgcn_mfma_f32_16x16x32_bf16(a1, bkreg[kt][0], Kacc[1][0], 0, 0, 0);
                Kacc[1][1] = __builtin_amdgcn_mfma_f32_16x16x32_bf16(a1, bkreg[kt][1], Kacc[1][1], 0, 0, 0);
            }
#pragma unroll
            for (int i = 0; i < 2; ++i)
#pragma unroll
                for (int r = 0; r < 4; ++r) {
                    float s = (float)qb[i][0][r] * Kacc[i][0][r]
                            + (float)qb[i][1][r] * Kacc[i][1][r];
                    s += __shfl_xor(s, 1);
                    s += __shfl_xor(s, 2);
                    s += __shfl_xor(s, 4);
                    s += __shfl_xor(s, 8);        // full row dot over 32 cols
                    const float mn = fmaxf(m[i][r], s);
                    const float f  = __expf(m[i][r] - mn);
                    const float e  = __expf(s - mn);
                    den[i][r] = den[i][r] * f + e;
                    m[i][r]   = mn;
                    if (rl == 0) {
                        const int row = i * 16 + g * 4 + r;
                        ef_lds[buf][h][row][0] = e;
                        ef_lds[buf][h][row][1] = f;
                    }
                }
            __syncthreads();                      // B3..B8: ef valid, next tile in
        }
#pragma unroll
        for (int i = 0; i < 2; ++i)
#pragma unroll
            for (int r = 0; r < 4; ++r)
                if (rl == 0) inv_lds[h][i * 16 + g * 4 + r] = 1.f / den[i][r];
        __syncthreads();                          // B9: inv published
        __syncthreads();                          // B10: attn tile written (by V)
    } else {
        // ================= V-role: head h = wv-8 =================
        const int h = wv - 8;
        bf16x8 bvreg[8][2];
#pragma unroll
        for (int kt = 0; kt < 8; ++kt)
#pragma unroll
            for (int j = 0; j < 2; ++j)
                bvreg[kt][j] = *(const bf16x8*)(Wv + (size_t)(h * 32 + j * 16 + rl) * 256 + kt * 32 + g * 8);
        stageA(0, xt + (size_t)(b * NV) * SL);
        stageA(1, xbar + (size_t)b * SL);
        __syncthreads();                          // B1

        f32x4 oacc[2][2];
#pragma unroll
        for (int i = 0; i < 2; ++i)
#pragma unroll
            for (int j = 0; j < 2; ++j) {
                oacc[i][j][0] = 0.f; oacc[i][j][1] = 0.f;
                oacc[i][j][2] = 0.f; oacc[i][j][3] = 0.f;
            }
        __syncthreads();                          // B2

        for (int v = 0; v < NV; ++v) {
            const int buf = v & 1;
            if (v < NV - 1) stageA(buf ^ 1, xt + (size_t)(b * NV + v + 1) * SL);
            f32x4 Vacc[2][2];
#pragma unroll
            for (int i = 0; i < 2; ++i)
#pragma unroll
                for (int j = 0; j < 2; ++j) {
                    Vacc[i][j][0] = 0.f; Vacc[i][j][1] = 0.f;
                    Vacc[i][j][2] = 0.f; Vacc[i][j][3] = 0.f;
                }
#pragma unroll
            for (int kt = 0; kt < 8; ++kt) {
                bf16x8 a0 = ldA(buf, kt, 0), a1 = ldA(buf, kt, 1);
                Vacc[0][0] = __builtin_amdgcn_mfma_f32_16x16x32_bf16(a0, bvreg[kt][0], Vacc[0][0], 0, 0, 0);
                Vacc[0][1] = __builtin_amdgcn_mfma_f32_16x16x32_bf16(a0, bvreg[kt][1], Vacc[0][1], 0, 0, 0);
                Vacc[1][0] = __builtin_amdgcn_mfma_f32_16x16x32_bf16(a1, bvreg[kt][0], Vacc[1][0], 0, 0, 0);
                Vacc[1][1] = __builtin_amdgcn_mfma_f32_16x16x32_bf16(a1, bvreg[kt][1], Vacc[1][1], 0, 0, 0);
            }
            __syncthreads();                      // B3..B8: ef(v) valid
#pragma unroll
            for (int i = 0; i < 2; ++i)
#pragma unroll
                for (int r = 0; r < 4; ++r) {
                    const int row = i * 16 + g * 4 + r;
                    const float e = ef_lds[buf][h][row][0];
                    const float f = ef_lds[buf][h][row][1];
#pragma unroll
                    for (int j = 0; j < 2; ++j)
                        oacc[i][j][r] = oacc[i][j][r] * f + e * Vacc[i][j][r];
                }
        }
        __syncthreads();                          // B9: inv published (by K)
#pragma unroll
        for (int i = 0; i < 2; ++i)
#pragma unroll
            for (int r = 0; r < 4; ++r) {
                const int row = i * 16 + g * 4 + r;
                const float inv = inv_lds[h][row];
#pragma unroll
                for (int j = 0; j < 2; ++j) {
                    const int c = h * 32 + j * 16 + rl;
                    Abuf[0][(c >> 3) * 256 + row * 8 + (c & 7)] =
                        __float2bfloat16(oacc[i][j][r] * inv);
                }
            }
        __syncthreads();                          // B10: attn tile ready
    }

    // ---- reconverged: Wo GEMM, wave wv owns cols wv*16..+15 ----
    f32x4 acc2[2];
#pragma unroll
    for (int i = 0; i < 2; ++i) {
        acc2[i][0] = 0.f; acc2[i][1] = 0.f; acc2[i][2] = 0.f; acc2[i][3] = 0.f;
    }
#pragma unroll
    for (int kt = 0; kt < 8; ++kt) {
        bf16x8 bo = *(const bf16x8*)(Wo + (size_t)(wv * 16 + rl) * 256 + kt * 32 + g * 8);
        bf16x8 a0 = ldA(0, kt, 0), a1 = ldA(0, kt, 1);
        acc2[0] = __builtin_amdgcn_mfma_f32_16x16x32_bf16(a0, bo, acc2[0], 0, 0, 0);
        acc2[1] = __builtin_amdgcn_mfma_f32_16x16x32_bf16(a1, bo, acc2[1], 0, 0, 0);
    }
    float* op = out + (size_t)b * C_DIM * HW;
    const int col = wv * 16 + rl;
#pragma unroll
    for (int i = 0; i < 2; ++i)
        *(f32x4*)(op + (size_t)col * HW + w0 + i * 16 + g * 4) = acc2[i];
}

extern "C" void kernel_launch(void* const* d_in, const int* in_sizes, int n_in,
                              void* d_out, int out_size, void* d_ws, size_t ws_size,
                              hipStream_t stream)
{
    const float* x  = (const float*)d_in[0];
    const float* Wq = (const float*)d_in[1];
    const float* Wk = (const float*)d_in[2];
    const float* Wv = (const float*)d_in[3];
    const float* Wo = (const float*)d_in[4];
    (void)in_sizes; (void)n_in; (void)out_size; (void)ws_size;

    char* ws = (char*)d_ws;
    const size_t MB = 1024ull * 1024ull;
    const size_t SL = (size_t)HW * C_DIM;

    __hip_bfloat16* Wbf  = (__hip_bfloat16*)(ws);            // 512 KB
    __hip_bfloat16* xt   = (__hip_bfloat16*)(ws + 1 * MB);   // 48 MB [4*6][4096][256]
    __hip_bfloat16* xbar = (__hip_bfloat16*)(ws + 49 * MB);  // 8 MB  [4][4096][256]

    const __hip_bfloat16* WqB = Wbf;
    const __hip_bfloat16* WkB = Wbf + 65536;
    const __hip_bfloat16* WvB = Wbf + 131072;
    const __hip_bfloat16* WoB = Wbf + 196608;

    convert_weights_kernel<<<dim3(256, 4), 256, 0, stream>>>(Wq, Wk, Wv, Wo, Wbf);
    transpose_mean_kernel<<<dim3(HW / 64, C_DIM / 64, NB), 256, 0, stream>>>(x, xt, xbar);
    mega_kernel<<<dim3(HW / 32, NB), 1024, 0, stream>>>(xt, xbar, WqB, WkB, WvB, WoB, (float*)d_out);
}

// Round 16
// 139.117 us; speedup vs baseline: 1.0037x; 1.0037x over previous
//
#include <hip/hip_runtime.h>
#include <hip/hip_bf16.h>

// CrossViewAttention: B=4, V=6, C=256, H=W=64 (HW=4096), heads=8, dh=32.
//
// Pipeline (3 launches): convert_weights, transpose_mean, mega_kernel.
//
// Round-15 mega: wave-role split. 1024 threads = 16 waves; block owns 32 px.
//   K-waves (0-7, head h): Wk head-slice RESIDENT in 64 VGPR; Q GEMM + qb;
//     per view: gemmK (LDS A + reg B), scores via lane-local product +
//     16-lane shfl butterfly, online-softmax stats, publish (e,f) to LDS.
//   V-waves (8-15, head h): Wv slice resident; per view: gemmV, then after
//     the barrier fold oacc = oacc*f + e*Vacc (overlaps K's next gemm).
//   Role branches are disjoint top-level 'if's so bkreg/bvreg live ranges
//   never overlap -> no 128-VGPR spill (rounds 9-13's poison). Inner loop has
//   ZERO global loads. One barrier per view. LDS 37 KB, 4 waves/SIMD.
// (Round-14 failed: a 256x256 bf16 matrix is 128 KB/matrix -> Wk+Wv = 256 KB
//  cannot live in LDS; stageW overflowed its 64 KB buffer.)

typedef __bf16 bf16x8 __attribute__((ext_vector_type(8)));
typedef __bf16 bf16x4 __attribute__((ext_vector_type(4)));
typedef float f32x4 __attribute__((ext_vector_type(4)));

#define HW 4096
#define C_DIM 256
#define NV 6
#define NB 4

__global__ __launch_bounds__(256) void convert_weights_kernel(
    const float* __restrict__ Wq, const float* __restrict__ Wk,
    const float* __restrict__ Wv, const float* __restrict__ Wo,
    __hip_bfloat16* __restrict__ out)
{
    const float* srcs[4] = {Wq, Wk, Wv, Wo};
    const int m = blockIdx.y;
    const int i = blockIdx.x * 256 + threadIdx.x;
    out[m * 65536 + i] = __float2bfloat16(srcs[m][i]);
}

// 64x64 tile transpose via LDS; accumulates per-view sum for xbar.
__global__ __launch_bounds__(256) void transpose_mean_kernel(
    const float* __restrict__ x,        // [B][V][C][HW]
    __hip_bfloat16* __restrict__ xt,    // [B][V][HW][C]
    __hip_bfloat16* __restrict__ xbar)  // [B][HW][C]
{
    __shared__ float tile[64][65];
    const int w0 = blockIdx.x * 64;
    const int c0 = blockIdx.y * 64;
    const int b  = blockIdx.z;
    const int t  = threadIdx.x;
    const int li = t & 63;
    const int qi = t >> 6;
    float acc[16];
#pragma unroll
    for (int i = 0; i < 16; ++i) acc[i] = 0.f;

    for (int v = 0; v < NV; ++v) {
        const float* src = x + (((size_t)b * NV + v) * C_DIM + c0) * HW + w0;
#pragma unroll
        for (int i = 0; i < 16; ++i) {
            const int c = qi + 4 * i;
            tile[li][c] = src[(size_t)c * HW + li];
        }
        __syncthreads();
        __hip_bfloat16* dst = xt + (((size_t)b * NV + v) * HW + w0) * C_DIM + c0;
#pragma unroll
        for (int i = 0; i < 16; ++i) {
            const int w = qi + 4 * i;
            const float val = tile[w][li];
            acc[i] += val;
            dst[(size_t)w * C_DIM + li] = __float2bfloat16(val);
        }
        __syncthreads();
    }
    __hip_bfloat16* dbar = xbar + ((size_t)b * HW + w0) * C_DIM + c0;
#pragma unroll
    for (int i = 0; i < 16; ++i) {
        const int w = qi + 4 * i;
        dbar[(size_t)w * C_DIM + li] = __float2bfloat16(acc[i] * (1.f / 6.f));
    }
}

// Mega kernel v4: 1024 threads (16 waves), block owns 32 pixels of batch b.
// Per-wave GEMM: M=32 (i<2), N=32 (j<2), K=256 (kt<8).
// Abuf layout: [kb 0..31][row 0..31][8] bf16 (16 KB per buffer, dbuf).
// ef[buf][head][row] = (e, f) softmax factors; inv_lds[head][row] = 1/den.
__global__ __launch_bounds__(1024, 4) void mega_kernel(
    const __hip_bfloat16* __restrict__ xt,    // [B*V][4096][256]
    const __hip_bfloat16* __restrict__ xbar,  // [B][4096][256]
    const __hip_bfloat16* __restrict__ Wq,
    const __hip_bfloat16* __restrict__ Wk,
    const __hip_bfloat16* __restrict__ Wv,
    const __hip_bfloat16* __restrict__ Wo,
    float* __restrict__ out)                  // [B][256][4096]
{
    __shared__ __align__(16) __hip_bfloat16 Abuf[2][8192];   // 2 x 16 KB
    __shared__ float ef_lds[2][8][32][2];                    // 4 KB
    __shared__ float inv_lds[8][32];                         // 1 KB
    const size_t SL = (size_t)HW * C_DIM;
    const int w0 = blockIdx.x * 32;
    const int b  = blockIdx.y;
    const int t  = threadIdx.x, wv = t >> 6, l = t & 63;
    const int g = l >> 4, rl = l & 15;

    // stage chunk wv (1 KB) of a 32x256 bf16 tile; 16 waves cover the tile.
    // chunk wv: kb = wv*2 + (l>>5), row = l&31; LDS dest wave-uniform.
    auto stageA = [&](int buf, const __hip_bfloat16* src) {
        const __hip_bfloat16* gp =
            src + (size_t)(w0 + (l & 31)) * 256 + (wv * 2 + (l >> 5)) * 8;
        __builtin_amdgcn_global_load_lds(
            (const __attribute__((address_space(1))) void*)gp,
            (__attribute__((address_space(3))) void*)(&Abuf[buf][wv * 512]),
            16, 0, 0);
    };
    auto ldA = [&](int buf, int kt, int i) -> bf16x8 {
        return *(const bf16x8*)&Abuf[buf][(kt * 4 + g) * 256 + (i * 16 + rl) * 8];
    };

    if (wv < 8) {
        // ================= K-role: head h = wv =================
        const int h = wv;
        bf16x8 bkreg[8][2];
#pragma unroll
        for (int kt = 0; kt < 8; ++kt)
#pragma unroll
            for (int j = 0; j < 2; ++j)
                bkreg[kt][j] = *(const bf16x8*)(Wk + (size_t)(h * 32 + j * 16 + rl) * 256 + kt * 32 + g * 8);
        stageA(0, xt + (size_t)(b * NV) * SL);   // view 0
        stageA(1, xbar + (size_t)b * SL);        // xbar for Q
        __syncthreads();                          // B1: tiles staged

        f32x4 Kacc[2][2];
#pragma unroll
        for (int i = 0; i < 2; ++i)
#pragma unroll
            for (int j = 0; j < 2; ++j) {
                Kacc[i][j][0] = 0.f; Kacc[i][j][1] = 0.f;
                Kacc[i][j][2] = 0.f; Kacc[i][j][3] = 0.f;
            }
#pragma unroll
        for (int kt = 0; kt < 8; ++kt) {
            bf16x8 b0 = *(const bf16x8*)(Wq + (size_t)(h * 32 + rl) * 256 + kt * 32 + g * 8);
            bf16x8 b1 = *(const bf16x8*)(Wq + (size_t)(h * 32 + 16 + rl) * 256 + kt * 32 + g * 8);
            bf16x8 a0 = ldA(1, kt, 0), a1 = ldA(1, kt, 1);
            Kacc[0][0] = __builtin_amdgcn_mfma_f32_16x16x32_bf16(a0, b0, Kacc[0][0], 0, 0, 0);
            Kacc[0][1] = __builtin_amdgcn_mfma_f32_16x16x32_bf16(a0, b1, Kacc[0][1], 0, 0, 0);
            Kacc[1][0] = __builtin_amdgcn_mfma_f32_16x16x32_bf16(a1, b0, Kacc[1][0], 0, 0, 0);
            Kacc[1][1] = __builtin_amdgcn_mfma_f32_16x16x32_bf16(a1, b1, Kacc[1][1], 0, 0, 0);
        }
        const float scale = 0.17677669529663687f; // 32^-0.5
        bf16x4 qb[2][2];
#pragma unroll
        for (int i = 0; i < 2; ++i)
#pragma unroll
            for (int j = 0; j < 2; ++j)
#pragma unroll
                for (int r = 0; r < 4; ++r)
                    qb[i][j][r] = (__bf16)(Kacc[i][j][r] * scale);
        float m[2][4], den[2][4];
#pragma unroll
        for (int i = 0; i < 2; ++i)
#pragma unroll
            for (int r = 0; r < 4; ++r) { m[i][r] = -1e30f; den[i][r] = 0.f; }
        __syncthreads();                          // B2: Q done, Abuf[1] free

        for (int v = 0; v < NV; ++v) {
            const int buf = v & 1;
            if (v < NV - 1) stageA(buf ^ 1, xt + (size_t)(b * NV + v + 1) * SL);
#pragma unroll
            for (int i = 0; i < 2; ++i)
#pragma unroll
                for (int j = 0; j < 2; ++j) {
                    Kacc[i][j][0] = 0.f; Kacc[i][j][1] = 0.f;
                    Kacc[i][j][2] = 0.f; Kacc[i][j][3] = 0.f;
                }
#pragma unroll
            for (int kt = 0; kt < 8; ++kt) {
                bf16x8 a0 = ldA(buf, kt, 0), a1 = ldA(buf, kt, 1);
                Kacc[0][0] = __builtin_amdgcn_mfma_f32_16x16x32_bf16(a0, bkreg[kt][0], Kacc[0][0], 0, 0, 0);
                Kacc[0][1] = __builtin_amdgcn_mfma_f32_16x16x32_bf16(a0, bkreg[kt][1], Kacc[0][1], 0, 0, 0);
                Kacc[1][0] = __builtin_amdgcn_mfma_f32_16x16x32_bf16(a1, bkreg[kt][0], Kacc[1][0], 0, 0, 0);
                Kacc[1][1] = __builtin_amdgcn_mfma_f32_16x16x32_bf16(a1, bkreg[kt][1], Kacc[1][1], 0, 0, 0);
            }
#pragma unroll
            for (int i = 0; i < 2; ++i)
#pragma unroll
                for (int r = 0; r < 4; ++r) {
                    float s = (float)qb[i][0][r] * Kacc[i][0][r]
                            + (float)qb[i][1][r] * Kacc[i][1][r];
                    s += __shfl_xor(s, 1);
                    s += __shfl_xor(s, 2);
                    s += __shfl_xor(s, 4);
                    s += __shfl_xor(s, 8);        // full row dot over 32 cols
                    const float mn = fmaxf(m[i][r], s);
                    const float f  = __expf(m[i][r] - mn);
                    const float e  = __expf(s - mn);
                    den[i][r] = den[i][r] * f + e;
                    m[i][r]   = mn;
                    if (rl == 0) {
                        const int row = i * 16 + g * 4 + r;
                        ef_lds[buf][h][row][0] = e;
                        ef_lds[buf][h][row][1] = f;
                    }
                }
            __syncthreads();                      // B3..B8: ef valid, next tile in
        }
#pragma unroll
        for (int i = 0; i < 2; ++i)
#pragma unroll
            for (int r = 0; r < 4; ++r)
                if (rl == 0) inv_lds[h][i * 16 + g * 4 + r] = 1.f / den[i][r];
        __syncthreads();                          // B9: inv published
        __syncthreads();                          // B10: attn tile written (by V)
    } else {
        // ================= V-role: head h = wv-8 =================
        const int h = wv - 8;
        bf16x8 bvreg[8][2];
#pragma unroll
        for (int kt = 0; kt < 8; ++kt)
#pragma unroll
            for (int j = 0; j < 2; ++j)
                bvreg[kt][j] = *(const bf16x8*)(Wv + (size_t)(h * 32 + j * 16 + rl) * 256 + kt * 32 + g * 8);
        stageA(0, xt + (size_t)(b * NV) * SL);
        stageA(1, xbar + (size_t)b * SL);
        __syncthreads();                          // B1

        f32x4 oacc[2][2];
#pragma unroll
        for (int i = 0; i < 2; ++i)
#pragma unroll
            for (int j = 0; j < 2; ++j) {
                oacc[i][j][0] = 0.f; oacc[i][j][1] = 0.f;
                oacc[i][j][2] = 0.f; oacc[i][j][3] = 0.f;
            }
        __syncthreads();                          // B2

        for (int v = 0; v < NV; ++v) {
            const int buf = v & 1;
            if (v < NV - 1) stageA(buf ^ 1, xt + (size_t)(b * NV + v + 1) * SL);
            f32x4 Vacc[2][2];
#pragma unroll
            for (int i = 0; i < 2; ++i)
#pragma unroll
                for (int j = 0; j < 2; ++j) {
                    Vacc[i][j][0] = 0.f; Vacc[i][j][1] = 0.f;
                    Vacc[i][j][2] = 0.f; Vacc[i][j][3] = 0.f;
                }
#pragma unroll
            for (int kt = 0; kt < 8; ++kt) {
                bf16x8 a0 = ldA(buf, kt, 0), a1 = ldA(buf, kt, 1);
                Vacc[0][0] = __builtin_amdgcn_mfma_f32_16x16x32_bf16(a0, bvreg[kt][0], Vacc[0][0], 0, 0, 0);
                Vacc[0][1] = __builtin_amdgcn_mfma_f32_16x16x32_bf16(a0, bvreg[kt][1], Vacc[0][1], 0, 0, 0);
                Vacc[1][0] = __builtin_amdgcn_mfma_f32_16x16x32_bf16(a1, bvreg[kt][0], Vacc[1][0], 0, 0, 0);
                Vacc[1][1] = __builtin_amdgcn_mfma_f32_16x16x32_bf16(a1, bvreg[kt][1], Vacc[1][1], 0, 0, 0);
            }
            __syncthreads();                      // B3..B8: ef(v) valid
#pragma unroll
            for (int i = 0; i < 2; ++i)
#pragma unroll
                for (int r = 0; r < 4; ++r) {
                    const int row = i * 16 + g * 4 + r;
                    const float e = ef_lds[buf][h][row][0];
                    const float f = ef_lds[buf][h][row][1];
#pragma unroll
                    for (int j = 0; j < 2; ++j)
                        oacc[i][j][r] = oacc[i][j][r] * f + e * Vacc[i][j][r];
                }
        }
        __syncthreads();                          // B9: inv published (by K)
#pragma unroll
        for (int i = 0; i < 2; ++i)
#pragma unroll
            for (int r = 0; r < 4; ++r) {
                const int row = i * 16 + g * 4 + r;
                const float inv = inv_lds[h][row];
#pragma unroll
                for (int j = 0; j < 2; ++j) {
                    const int c = h * 32 + j * 16 + rl;
                    Abuf[0][(c >> 3) * 256 + row * 8 + (c & 7)] =
                        __float2bfloat16(oacc[i][j][r] * inv);
                }
            }
        __syncthreads();                          // B10: attn tile ready
    }

    // ---- reconverged: Wo GEMM, wave wv owns cols wv*16..+15 ----
    f32x4 acc2[2];
#pragma unroll
    for (int i = 0; i < 2; ++i) {
        acc2[i][0] = 0.f; acc2[i][1] = 0.f; acc2[i][2] = 0.f; acc2[i][3] = 0.f;
    }
#pragma unroll
    for (int kt = 0; kt < 8; ++kt) {
        bf16x8 bo = *(const bf16x8*)(Wo + (size_t)(wv * 16 + rl) * 256 + kt * 32 + g * 8);
        bf16x8 a0 = ldA(0, kt, 0), a1 = ldA(0, kt, 1);
        acc2[0] = __builtin_amdgcn_mfma_f32_16x16x32_bf16(a0, bo, acc2[0], 0, 0, 0);
        acc2[1] = __builtin_amdgcn_mfma_f32_16x16x32_bf16(a1, bo, acc2[1], 0, 0, 0);
    }
    float* op = out + (size_t)b * C_DIM * HW;
    const int col = wv * 16 + rl;
#pragma unroll
    for (int i = 0; i < 2; ++i)
        *(f32x4*)(op + (size_t)col * HW + w0 + i * 16 + g * 4) = acc2[i];
}

extern "C" void kernel_launch(void* const* d_in, const int* in_sizes, int n_in,
                              void* d_out, int out_size, void* d_ws, size_t ws_size,
                              hipStream_t stream)
{
    const float* x  = (const float*)d_in[0];
    const float* Wq = (const float*)d_in[1];
    const float* Wk = (const float*)d_in[2];
    const float* Wv = (const float*)d_in[3];
    const float* Wo = (const float*)d_in[4];
    (void)in_sizes; (void)n_in; (void)out_size; (void)ws_size;

    char* ws = (char*)d_ws;
    const size_t MB = 1024ull * 1024ull;
    const size_t SL = (size_t)HW * C_DIM;

    __hip_bfloat16* Wbf  = (__hip_bfloat16*)(ws);            // 512 KB
    __hip_bfloat16* xt   = (__hip_bfloat16*)(ws + 1 * MB);   // 48 MB [4*6][4096][256]
    __hip_bfloat16* xbar = (__hip_bfloat16*)(ws + 49 * MB);  // 8 MB  [4][4096][256]

    const __hip_bfloat16* WqB = Wbf;
    const __hip_bfloat16* WkB = Wbf + 65536;
    const __hip_bfloat16* WvB = Wbf + 131072;
    const __hip_bfloat16* WoB = Wbf + 196608;

    convert_weights_kernel<<<dim3(256, 4), 256, 0, stream>>>(Wq, Wk, Wv, Wo, Wbf);
    transpose_mean_kernel<<<dim3(HW / 64, C_DIM / 64, NB), 256, 0, stream>>>(x, xt, xbar);
    mega_kernel<<<dim3(HW / 32, NB), 1024, 0, stream>>>(xt, xbar, WqB, WkB, WvB, WoB, (float*)d_out);
}